// Round 1
// baseline (316.187 us; speedup 1.0000x reference)
//
#include <hip/hip_runtime.h>
#include <hip/hip_bf16.h>
#include <math.h>

// Problem constants (match reference)
#define E_EDGES 262144
#define NBUCKET 8192
#define DEG     32
#define FDIM    128   // in_feats == out_feats == 128

typedef float f32x4 __attribute__((ext_vector_type(4)));
typedef short s16x8 __attribute__((ext_vector_type(8)));
typedef short s16x4 __attribute__((ext_vector_type(4)));

__device__ __forceinline__ short f2bf(float f) {
    union { float f; unsigned u; } v; v.f = f;
    unsigned r = v.u + 0x7FFFu + ((v.u >> 16) & 1u);   // RNE
    return (short)(r >> 16);
}
__device__ __forceinline__ float bf2f(short s) {
    union { unsigned u; float f; } v; v.u = ((unsigned)(unsigned short)s) << 16;
    return v.f;
}

// Stage a 128x128 f32 weight block (row stride `stride` floats) into LDS as
// bf16, row-major with XOR swizzle on byte bits [6:4]: byte ^= (n&7)<<4.
// This spreads stride-256B column reads across 8 bank groups (<=2-way, free).
__device__ __forceinline__ void stage_w(short* w_lds, const float* __restrict__ Wg,
                                        int stride, int tid) {
    #pragma unroll
    for (int it = 0; it < 16; ++it) {
        int i  = it * 256 + tid;        // float4 index, 0..4095
        int n  = i >> 5;                // row (32 float4 per row)
        int k4 = (i & 31) << 2;         // element offset in row
        const float4 v = *reinterpret_cast<const float4*>(Wg + (size_t)n * stride + k4);
        s16x4 h; h[0]=f2bf(v.x); h[1]=f2bf(v.y); h[2]=f2bf(v.z); h[3]=f2bf(v.w);
        int byte = ((n << 8) + (k4 << 1)) ^ ((n & 7) << 4);
        *reinterpret_cast<s16x4*>(reinterpret_cast<char*>(w_lds) + byte) = h;
    }
}

// B-fragment read from swizzled LDS weights: lane needs W[n][k0..k0+7] (bf16),
// n = nt*16 + (lane&15), k0 = kb*32 + ((lane>>4)<<3)
__device__ __forceinline__ s16x8 read_wfrag(const short* w_lds, int n, int k0) {
    int byte = ((n << 8) + (k0 << 1)) ^ ((n & 7) << 4);
    return *reinterpret_cast<const s16x8*>(reinterpret_cast<const char*>(w_lds) + byte);
}

// ---------------------------------------------------------------------------
// Phase 1: enc_src/enc_dst = relu([feat | cos(t*w+p)] @ W_time^T + b_time), bf16
// Block: 256 thr (4 waves), 64 edge-rows; wave w owns rows r0+w*16 .. +15.
// S = T·W2^T computed once (shared by src & dst), then acc = S + feat·W1^T.
// ---------------------------------------------------------------------------
__global__ __launch_bounds__(256, 2)
void encode_kernel(const float* __restrict__ src_feat,
                   const float* __restrict__ dst_feat,
                   const float* __restrict__ ts,
                   const float* __restrict__ freq,
                   const float* __restrict__ ph,
                   const float* __restrict__ W_time,   // [128][256]
                   const float* __restrict__ b_time,   // [128]
                   short* __restrict__ enc_src,        // [E][128] bf16
                   short* __restrict__ enc_dst)
{
    __shared__ short w_lds[128 * 128];   // 32 KB, reused W2 -> W1

    const int tid  = threadIdx.x;
    const int lane = tid & 63;
    const int wid  = tid >> 6;
    const int r0   = blockIdx.x * 64 + wid * 16;
    const int lrow = lane & 15;
    const int klo  = (lane >> 4) << 3;

    // stage W2 = W_time[:,128:256]
    stage_w(w_lds, W_time + 128, 256, tid);

    // T fragments: tt[row][k] = cos(t_row * freq[k] + ph[k])
    const float t_row = ts[r0 + lrow];
    s16x8 tf[4];
    #pragma unroll
    for (int kb = 0; kb < 4; ++kb) {
        const int k = kb * 32 + klo;
        s16x8 t;
        #pragma unroll
        for (int j = 0; j < 8; ++j)
            t[j] = f2bf(cosf(fmaf(t_row, freq[k + j], ph[k + j])));
        tf[kb] = t;
    }

    __syncthreads();

    // S = T * W2^T   (8 n-tiles x 4 k-blocks)
    f32x4 S[8];
    #pragma unroll
    for (int nt = 0; nt < 8; ++nt) {
        f32x4 a = {0.f, 0.f, 0.f, 0.f};
        #pragma unroll
        for (int kb = 0; kb < 4; ++kb)
            a = __builtin_amdgcn_mfma_f32_16x16x32_bf16(
                    tf[kb], read_wfrag(w_lds, nt * 16 + lrow, kb * 32 + klo), a, 0, 0, 0);
        S[nt] = a;
    }

    __syncthreads();
    // stage W1 = W_time[:,0:128]
    stage_w(w_lds, W_time, 256, tid);
    __syncthreads();

    #pragma unroll
    for (int s = 0; s < 2; ++s) {
        const float* feat = s ? dst_feat : src_feat;
        short*       enc  = s ? enc_dst  : enc_src;

        s16x8 af[4];
        #pragma unroll
        for (int kb = 0; kb < 4; ++kb) {
            const float* p = feat + (size_t)(r0 + lrow) * FDIM + kb * 32 + klo;
            const float4 lo = *reinterpret_cast<const float4*>(p);
            const float4 hi = *reinterpret_cast<const float4*>(p + 4);
            s16x8 a;
            a[0]=f2bf(lo.x); a[1]=f2bf(lo.y); a[2]=f2bf(lo.z); a[3]=f2bf(lo.w);
            a[4]=f2bf(hi.x); a[5]=f2bf(hi.y); a[6]=f2bf(hi.z); a[7]=f2bf(hi.w);
            af[kb] = a;
        }

        #pragma unroll
        for (int nt = 0; nt < 8; ++nt) {
            f32x4 acc = S[nt];
            #pragma unroll
            for (int kb = 0; kb < 4; ++kb)
                acc = __builtin_amdgcn_mfma_f32_16x16x32_bf16(
                        af[kb], read_wfrag(w_lds, nt * 16 + lrow, kb * 32 + klo), acc, 0, 0, 0);

            const int col  = nt * 16 + lrow;
            const float bias = b_time[col];
            const int rbase = r0 + ((lane >> 4) << 2);
            #pragma unroll
            for (int r = 0; r < 4; ++r) {
                float e = acc[r] + bias;
                e = e > 0.f ? e : 0.f;                      // relu
                enc[(size_t)(rbase + r) * FDIM + col] = f2bf(e);
            }
        }
    }
}

// ---------------------------------------------------------------------------
// Phase 2: per-bucket causal mean conv + scatter.
// grid = (NBUCKET/2, 2); block 256 thr (4 waves) handles 2 buckets.
// g=0: self=enc_src, neigh=enc_dst, src_perm/src_idx -> out[0]
// g=1: self=enc_dst, neigh=enc_src, dst_perm/dst_idx -> out[1]
// hf[j] = cumsum(hn)[j] / (idx[j]+1)  (bf16, swizzled LDS rows)
// rst[d] = hs[d]·Wself^T + hf[idx[d]]·Wneigh^T + (b_self+b_neigh)
// out[perm[d]] = rst[d]
// ---------------------------------------------------------------------------
__global__ __launch_bounds__(256, 2)
void conv_kernel(const short* __restrict__ enc_src,
                 const short* __restrict__ enc_dst,
                 const float* __restrict__ W_self,
                 const float* __restrict__ b_self,
                 const float* __restrict__ W_neigh,
                 const float* __restrict__ b_neigh,
                 const int* __restrict__ src_perm,
                 const int* __restrict__ dst_perm,
                 const int* __restrict__ src_idx,
                 const int* __restrict__ dst_idx,
                 float* __restrict__ out)        // [2][E][128] f32
{
    __shared__ short w_lds[128 * 128];   // 32 KB, Wself -> Wneigh
    __shared__ short hf[2][DEG * 128];   // 16 KB, swizzled rows
    __shared__ int   perm_s[2][DEG];
    __shared__ int   idx_s[2][DEG];
    __shared__ float bias_s[128];

    const int tid = threadIdx.x;
    const int g   = blockIdx.y;
    const int b0  = blockIdx.x * 2;

    const short* enc_self  = g ? enc_dst : enc_src;
    const short* enc_neigh = g ? enc_src : enc_dst;
    const int*   perm      = g ? dst_perm : src_perm;
    const int*   degi      = g ? dst_idx  : src_idx;
    float*       outg      = out + (size_t)g * E_EDGES * FDIM;

    if (tid < 64) {
        const int lb = tid >> 5, d = tid & 31;
        perm_s[lb][d] = perm[(b0 + lb) * DEG + d];
        idx_s[lb][d]  = degi[(b0 + lb) * DEG + d];
    } else if (tid < 192) {
        const int c = tid - 64;
        bias_s[c] = b_self[c] + b_neigh[c];
    }
    stage_w(w_lds, W_self, 128, tid);
    __syncthreads();

    // causal cumsum -> hf (128 threads per bucket; thread owns one channel)
    {
        const int lb = tid >> 7;
        const int c  = tid & 127;
        float run = 0.f;
        #pragma unroll
        for (int d = 0; d < DEG; ++d) {
            const int e = perm_s[lb][d];
            run += bf2f(enc_neigh[(size_t)e * FDIM + c]);
            const float inv = 1.f / (float)(idx_s[lb][d] + 1);
            const int byte = ((d << 8) + (c << 1)) ^ ((d & 7) << 4);
            *reinterpret_cast<short*>(reinterpret_cast<char*>(hf[lb]) + byte)
                = f2bf(run * inv);
        }
    }

    const int lane = tid & 63;
    const int wid  = tid >> 6;
    const int lb   = wid >> 1;      // bucket within block
    const int mt   = wid & 1;       // 16-row m-tile within bucket
    const int lrow = lane & 15;
    const int klo  = (lane >> 4) << 3;
    const int row  = mt * 16 + lrow;

    // pass A: hs @ Wself^T  (hs fragments gathered straight from global)
    s16x8 hsf[4];
    {
        const int e = perm_s[lb][row];
        const short* p = enc_self + (size_t)e * FDIM;
        #pragma unroll
        for (int kb = 0; kb < 4; ++kb)
            hsf[kb] = *reinterpret_cast<const s16x8*>(p + kb * 32 + klo);
    }
    f32x4 acc[8];
    #pragma unroll
    for (int nt = 0; nt < 8; ++nt) {
        f32x4 a = {0.f, 0.f, 0.f, 0.f};
        #pragma unroll
        for (int kb = 0; kb < 4; ++kb)
            a = __builtin_amdgcn_mfma_f32_16x16x32_bf16(
                    hsf[kb], read_wfrag(w_lds, nt * 16 + lrow, kb * 32 + klo), a, 0, 0, 0);
        acc[nt] = a;
    }

    __syncthreads();
    stage_w(w_lds, W_neigh, 128, tid);
    __syncthreads();

    // pass B: hf[idx[row]] @ Wneigh^T, then epilogue + scatter
    s16x8 mff[4];
    {
        const int j = idx_s[lb][row];
        #pragma unroll
        for (int kb = 0; kb < 4; ++kb) {
            const int byte = ((j << 8) + ((kb * 32 + klo) << 1)) ^ ((j & 7) << 4);
            mff[kb] = *reinterpret_cast<const s16x8*>(
                          reinterpret_cast<const char*>(hf[lb]) + byte);
        }
    }
    #pragma unroll
    for (int nt = 0; nt < 8; ++nt) {
        f32x4 a = acc[nt];
        #pragma unroll
        for (int kb = 0; kb < 4; ++kb)
            a = __builtin_amdgcn_mfma_f32_16x16x32_bf16(
                    mff[kb], read_wfrag(w_lds, nt * 16 + lrow, kb * 32 + klo), a, 0, 0, 0);

        const int col = nt * 16 + lrow;
        const float bias = bias_s[col];
        #pragma unroll
        for (int r = 0; r < 4; ++r) {
            const int rr = mt * 16 + ((lane >> 4) << 2) + r;
            const int e  = perm_s[lb][rr];
            outg[(size_t)e * FDIM + col] = a[r] + bias;
        }
    }
}

extern "C" void kernel_launch(void* const* d_in, const int* in_sizes, int n_in,
                              void* d_out, int out_size, void* d_ws, size_t ws_size,
                              hipStream_t stream) {
    (void)in_sizes; (void)n_in; (void)out_size; (void)ws_size;

    const float* src_feat = (const float*)d_in[0];
    const float* dst_feat = (const float*)d_in[1];
    const float* ts       = (const float*)d_in[2];
    const float* freq     = (const float*)d_in[3];
    const float* ph       = (const float*)d_in[4];
    const float* W_time   = (const float*)d_in[5];
    const float* b_time   = (const float*)d_in[6];
    const float* W_self   = (const float*)d_in[7];
    const float* b_self   = (const float*)d_in[8];
    const float* W_neigh  = (const float*)d_in[9];
    const float* b_neigh  = (const float*)d_in[10];
    const int*   src_perm = (const int*)d_in[11];
    const int*   dst_perm = (const int*)d_in[12];
    const int*   src_idx  = (const int*)d_in[13];
    const int*   dst_idx  = (const int*)d_in[14];

    // workspace: enc_src, enc_dst as bf16 [E][128]  (needs 128 MiB)
    short* enc_src = (short*)d_ws;
    short* enc_dst = enc_src + (size_t)E_EDGES * FDIM;

    encode_kernel<<<dim3(E_EDGES / 64), dim3(256), 0, stream>>>(
        src_feat, dst_feat, ts, freq, ph, W_time, b_time, enc_src, enc_dst);

    conv_kernel<<<dim3(NBUCKET / 2, 2), dim3(256), 0, stream>>>(
        enc_src, enc_dst, W_self, b_self, W_neigh, b_neigh,
        src_perm, dst_perm, src_idx, dst_idx, (float*)d_out);
}